// Round 7
// baseline (270.940 us; speedup 1.0000x reference)
//
#include <hip/hip_runtime.h>

// HenonLayer: 4x { t=tanh(Y@W_in+b); grad=((1-t^2)*W_out)@W_in.T; X'=Y+eta; Y'=-X+grad }
// B=2e6, DIM=2, NI=64, fp32, eps=1.
//
// Round-7: inline-asm VOP3P abandoned (rounds 4-6: two falsified routing
// theories, identical residual error across different code -> undiagnosable
// headlessly). Back to compiled scalar code (round-3 lineage) with two new
// levers, calibrated from R1/R2/R3 timings (v_rcp_f32 ~ 16 busy-cyc/wave):
//   1. Combined reciprocal: 1 rcp serves 4 rows' sech^2 per neuron
//      (inv = rcp(p0 p1 p2 p3), unwound with 9 muls; p <= ~1e8 so the
//      product is overflow-safe; added relative error ~1e-6).
//   2. 4 rows/thread slice-strided -> 500k threads = 7.6 waves/SIMD
//      (round 3 launched only 3.8 -> 25% idle).
// sech^2(a) = rcp(cosh^2(a)), cosh^2 = deg-5 all-positive Taylor in x=a^2
// (monotone >= 1, no branches, abs err <= ~3e-4; validated rounds 2-3).

#define NI 64

#define D5 1.410934744e-4f
#define D4 3.174603175e-3f
#define D3 4.444444444e-2f
#define D2 3.333333333e-1f

// d_ws table (floats): [0:64) w0 | [64:128) w1 | [128:192) b | [192:256) c0
// | [256:320) c1 | [320],[321] eta   (c = W_out * w)
__global__ __launch_bounds__(64) void henon_prep(
    const float* __restrict__ W_in, const float* __restrict__ W_out,
    const float* __restrict__ b_in, const float* __restrict__ eta,
    float* __restrict__ P) {
  int i = threadIdx.x;
  float w0 = W_in[i];
  float w1 = W_in[NI + i];
  float wo = W_out[i];
  P[i] = w0;
  P[NI + i] = w1;
  P[2 * NI + i] = b_in[i];
  P[3 * NI + i] = wo * w0;
  P[4 * NI + i] = wo * w1;
  if (i < 2) P[5 * NI + i] = eta[i];
}

__global__ __launch_bounds__(256) void henon_q(
    const float4* __restrict__ z, const float* __restrict__ P,
    float4* __restrict__ out, int batch, int T /* rows per slice */) {
  int t = blockIdx.x * blockDim.x + threadIdx.x;
  if (t >= T) return;

  float e0 = P[5 * NI], e1 = P[5 * NI + 1];

  // Rows t, t+T, t+2T, t+3T (adjacent lanes -> adjacent rows: coalesced).
  int r[4];
  bool ok[4];
  float X0[4], X1[4], Y0[4], Y1[4];
#pragma unroll
  for (int k = 0; k < 4; ++k) {
    r[k] = t + k * T;
    ok[k] = r[k] < batch;
    float4 v = ok[k] ? z[r[k]] : make_float4(0.f, 0.f, 0.f, 0.f);
    X0[k] = v.x; X1[k] = v.y; Y0[k] = v.z; Y1[k] = v.w;
  }

  // Loop-invariant poly constants (compiler hoists the materialization).
  const float d5 = D5, d4 = D4, d3 = D3, d2 = D2;

#pragma unroll 1
  for (int it = 0; it < 4; ++it) {
    float g0[4] = {0.f, 0.f, 0.f, 0.f};
    float g1[4] = {0.f, 0.f, 0.f, 0.f};
#pragma unroll
    for (int i = 0; i < NI; ++i) {
      // Uniform scalar loads (SALU); b copied to a VGPR once per neuron so
      // each preact fma has at most one SGPR operand (no per-row v_mov).
      float w0 = P[i];
      float w1 = P[NI + i];
      float bv = P[2 * NI + i];
      float c0 = P[3 * NI + i];
      float c1 = P[4 * NI + i];

      float p[4];
#pragma unroll
      for (int k = 0; k < 4; ++k) {
        float a = fmaf(Y0[k], w0, fmaf(Y1[k], w1, bv));
        float x = a * a;
        float q = fmaf(x, d5, d4);
        q = fmaf(q, x, d3);
        q = fmaf(q, x, d2);
        q = fmaf(q, x, 1.0f);
        q = fmaf(q, x, 1.0f);   // q = cosh^2(a) >= 1, <= ~1e8
        p[k] = q;
      }
      // One reciprocal for all four rows.
      float p01 = p[0] * p[1];
      float p23 = p[2] * p[3];
      float inv = __builtin_amdgcn_rcpf(p01 * p23);
      float i01 = inv * p23;           // 1/(p0 p1)
      float i23 = inv * p01;           // 1/(p2 p3)
      float s0 = i01 * p[1];           // sech^2 row 0
      float s1 = i01 * p[0];
      float s2 = i23 * p[3];
      float s3 = i23 * p[2];
      g0[0] = fmaf(s0, c0, g0[0]);  g1[0] = fmaf(s0, c1, g1[0]);
      g0[1] = fmaf(s1, c0, g0[1]);  g1[1] = fmaf(s1, c1, g1[1]);
      g0[2] = fmaf(s2, c0, g0[2]);  g1[2] = fmaf(s2, c1, g1[2]);
      g0[3] = fmaf(s3, c0, g0[3]);  g1[3] = fmaf(s3, c1, g1[3]);
    }
#pragma unroll
    for (int k = 0; k < 4; ++k) {
      float nX0 = Y0[k] + e0;
      float nX1 = Y1[k] + e1;
      Y0[k] = g0[k] - X0[k];
      Y1[k] = g1[k] - X1[k];
      X0[k] = nX0;
      X1[k] = nX1;
    }
  }

#pragma unroll
  for (int k = 0; k < 4; ++k) {
    if (ok[k]) out[r[k]] = make_float4(X0[k], X1[k], Y0[k], Y1[k]);
  }
}

// Fallback if ws too small for the table: raw weights, 1 row/thread.
__global__ __launch_bounds__(256) void henon_raw(
    const float4* __restrict__ z, const float* __restrict__ W_in,
    const float* __restrict__ W_out, const float* __restrict__ b_in,
    const float* __restrict__ eta, float4* __restrict__ out, int batch) {
  int idx = blockIdx.x * blockDim.x + threadIdx.x;
  int stride = gridDim.x * blockDim.x;
  float e0 = eta[0], e1 = eta[1];
  for (int row = idx; row < batch; row += stride) {
    float4 v = z[row];
    float X0 = v.x, X1 = v.y, Y0 = v.z, Y1 = v.w;
    for (int it = 0; it < 4; ++it) {
      float g0 = 0.f, g1 = 0.f;
#pragma unroll
      for (int i = 0; i < NI; ++i) {
        float w0 = W_in[i], w1 = W_in[NI + i];
        float a = fmaf(Y0, w0, fmaf(Y1, w1, b_in[i]));
        float x = a * a;
        float q = fmaf(x, D5, D4);
        q = fmaf(q, x, D3);
        q = fmaf(q, x, D2);
        q = fmaf(q, x, 1.0f);
        q = fmaf(q, x, 1.0f);
        float s = __builtin_amdgcn_rcpf(q) * W_out[i];
        g0 = fmaf(s, w0, g0);
        g1 = fmaf(s, w1, g1);
      }
      float nX0 = Y0 + e0, nX1 = Y1 + e1;
      Y0 = g0 - X0;
      Y1 = g1 - X1;
      X0 = nX0;
      X1 = nX1;
    }
    out[row] = make_float4(X0, X1, Y0, Y1);
  }
}

extern "C" void kernel_launch(void* const* d_in, const int* in_sizes, int n_in,
                              void* d_out, int out_size, void* d_ws, size_t ws_size,
                              hipStream_t stream) {
  const float4* z = (const float4*)d_in[0];
  const float* W_in = (const float*)d_in[1];
  const float* W_out = (const float*)d_in[2];
  const float* b_in = (const float*)d_in[3];
  const float* eta = (const float*)d_in[4];
  float4* out = (float4*)d_out;

  int batch = in_sizes[0] / 4;  // 2,000,000 rows

  if (ws_size >= (5 * NI + 2) * sizeof(float)) {
    float* P = (float*)d_ws;
    henon_prep<<<1, 64, 0, stream>>>(W_in, W_out, b_in, eta, P);
    int T = (batch + 3) >> 2;  // rows per slice == thread count
    int blocks = (T + 255) / 256;
    henon_q<<<blocks, 256, 0, stream>>>(z, P, out, batch, T);
  } else {
    int blocks = (batch + 255) / 256;
    henon_raw<<<blocks, 256, 0, stream>>>(z, W_in, W_out, b_in, eta, out, batch);
  }
}

// Round 8
// 235.031 us; speedup vs baseline: 1.1528x; 1.1528x over previous
//
#include <hip/hip_runtime.h>

// HenonLayer: 4x { t=tanh(Y@W_in+b); grad=((1-t^2)*W_out)@W_in.T; X'=Y+eta; Y'=-X+grad }
// B=2e6, DIM=2, NI=64, fp32, eps=1.
//
// Round-8: R3 (161us kernel, busy-cyc/row-visit = 37 ~= the 10-VALU + 1-rcp
// floor) was wave-starved: 8 rows/thread -> 250k threads = 3.8 waves/SIMD,
// VALUBusy 75%. R7's combined-rcp restructure doubled codegen (58 cyc/unit)
// and is abandoned. This round: R3's code verbatim with 4 rows/thread
// (2 float2 packs) -> 500k threads = 7.6 waves/SIMD to close the idle 25%.
// sech^2(a) = rcp(cosh^2(a)), cosh^2 = deg-5 all-positive Taylor in x=a^2
// (monotone >= 1, saturates cleanly, no branches; abs err <= ~3e-4).

#define NI 64

#define D5 1.410934744e-4f
#define D4 3.174603175e-3f
#define D3 4.444444444e-2f
#define D2 3.333333333e-1f

typedef float v2f __attribute__((ext_vector_type(2)));

__device__ __forceinline__ v2f splat(float s) { return (v2f){s, s}; }
__device__ __forceinline__ v2f vfma(v2f a, v2f b, v2f c) {
  return __builtin_elementwise_fma(a, b, c);
}
__device__ __forceinline__ v2f vrcp(v2f a) {
  v2f r;
  r.x = __builtin_amdgcn_rcpf(a.x);
  r.y = __builtin_amdgcn_rcpf(a.y);
  return r;
}

// d_ws table (floats): [0:128) w0 pairs | [128:256) w1 pairs | [256:384) b pairs
// | [384:512) c0 pairs | [512:640) c1 pairs | [640],[641] eta
__global__ __launch_bounds__(64) void henon_prep(
    const float* __restrict__ W_in, const float* __restrict__ W_out,
    const float* __restrict__ b_in, const float* __restrict__ eta,
    float* __restrict__ P) {
  int i = threadIdx.x;
  float w0 = W_in[i];
  float w1 = W_in[NI + i];
  float b = b_in[i];
  float wo = W_out[i];
  P[2 * i] = w0;       P[2 * i + 1] = w0;
  P[128 + 2 * i] = w1; P[128 + 2 * i + 1] = w1;
  P[256 + 2 * i] = b;  P[256 + 2 * i + 1] = b;
  float c0 = wo * w0, c1 = wo * w1;
  P[384 + 2 * i] = c0; P[384 + 2 * i + 1] = c0;
  P[512 + 2 * i] = c1; P[512 + 2 * i + 1] = c1;
  if (i < 2) P[640 + i] = eta[i];
}

__global__ __launch_bounds__(256) void henon4(
    const float4* __restrict__ z, const float* __restrict__ P,
    float4* __restrict__ out, int batch) {
  const v2f* __restrict__ Pw0 = (const v2f*)P;
  const v2f* __restrict__ Pw1 = (const v2f*)(P + 128);
  const v2f* __restrict__ Pb  = (const v2f*)(P + 256);
  const v2f* __restrict__ Pc0 = (const v2f*)(P + 384);
  const v2f* __restrict__ Pc1 = (const v2f*)(P + 512);
  float e0 = P[640], e1 = P[641];

  int tid = blockIdx.x * blockDim.x + threadIdx.x;
  int nthr = gridDim.x * blockDim.x;
  int ngroups = batch >> 2;

  for (int g = tid; g < ngroups; g += nthr) {
    int r = g << 2;
    float4 v[4];
#pragma unroll
    for (int k = 0; k < 4; ++k) v[k] = z[r + k];

    v2f X0[2], X1[2], Y0[2], Y1[2];
#pragma unroll
    for (int p = 0; p < 2; ++p) {
      X0[p] = (v2f){v[2 * p].x, v[2 * p + 1].x};
      X1[p] = (v2f){v[2 * p].y, v[2 * p + 1].y};
      Y0[p] = (v2f){v[2 * p].z, v[2 * p + 1].z};
      Y1[p] = (v2f){v[2 * p].w, v[2 * p + 1].w};
    }

    for (int it = 0; it < 4; ++it) {
      v2f g0[2], g1[2];
#pragma unroll
      for (int p = 0; p < 2; ++p) { g0[p] = splat(0.f); g1[p] = splat(0.f); }
#pragma unroll
      for (int i = 0; i < NI; ++i) {
        v2f w0 = Pw0[i], w1 = Pw1[i], b = Pb[i];
        v2f c0 = Pc0[i], c1 = Pc1[i];
#pragma unroll
        for (int p = 0; p < 2; ++p) {
          v2f a = vfma(Y0[p], w0, vfma(Y1[p], w1, b));
          v2f x = a * a;
          v2f q = vfma(x, splat(D5), splat(D4));
          q = vfma(q, x, splat(D3));
          q = vfma(q, x, splat(D2));
          q = vfma(q, x, splat(1.0f));
          q = vfma(q, x, splat(1.0f));
          v2f s = vrcp(q);
          g0[p] = vfma(s, c0, g0[p]);
          g1[p] = vfma(s, c1, g1[p]);
        }
      }
#pragma unroll
      for (int p = 0; p < 2; ++p) {
        v2f nX0 = Y0[p] + splat(e0);
        v2f nX1 = Y1[p] + splat(e1);
        Y0[p] = g0[p] - X0[p];
        Y1[p] = g1[p] - X1[p];
        X0[p] = nX0;
        X1[p] = nX1;
      }
    }
#pragma unroll
    for (int p = 0; p < 2; ++p) {
      out[r + 2 * p]     = make_float4(X0[p].x, X1[p].x, Y0[p].x, Y1[p].x);
      out[r + 2 * p + 1] = make_float4(X0[p].y, X1[p].y, Y0[p].y, Y1[p].y);
    }
  }

  // Tail rows (batch % 4), scalar path.
  int tail = batch & 3;
  if (tail && tid < tail) {
    int row = (ngroups << 2) + tid;
    float4 v = z[row];
    float X0 = v.x, X1 = v.y, Y0 = v.z, Y1 = v.w;
    for (int it = 0; it < 4; ++it) {
      float g0 = 0.f, g1 = 0.f;
      for (int i = 0; i < NI; ++i) {
        float a = fmaf(Y0, Pw0[i].x, fmaf(Y1, Pw1[i].x, Pb[i].x));
        float x = a * a;
        float q = fmaf(x, D5, D4);
        q = fmaf(q, x, D3);
        q = fmaf(q, x, D2);
        q = fmaf(q, x, 1.0f);
        q = fmaf(q, x, 1.0f);
        float s = __builtin_amdgcn_rcpf(q);
        g0 = fmaf(s, Pc0[i].x, g0);
        g1 = fmaf(s, Pc1[i].x, g1);
      }
      float nX0 = Y0 + e0, nX1 = Y1 + e1;
      Y0 = g0 - X0;
      Y1 = g1 - X1;
      X0 = nX0;
      X1 = nX1;
    }
    out[row] = make_float4(X0, X1, Y0, Y1);
  }
}

// Fallback if ws too small for the table: raw weights, 1 row/thread.
__global__ __launch_bounds__(256) void henon_raw(
    const float4* __restrict__ z, const float* __restrict__ W_in,
    const float* __restrict__ W_out, const float* __restrict__ b_in,
    const float* __restrict__ eta, float4* __restrict__ out, int batch) {
  int idx = blockIdx.x * blockDim.x + threadIdx.x;
  int stride = gridDim.x * blockDim.x;
  float e0 = eta[0], e1 = eta[1];
  for (int row = idx; row < batch; row += stride) {
    float4 v = z[row];
    float X0 = v.x, X1 = v.y, Y0 = v.z, Y1 = v.w;
    for (int it = 0; it < 4; ++it) {
      float g0 = 0.f, g1 = 0.f;
#pragma unroll
      for (int i = 0; i < NI; ++i) {
        float w0 = W_in[i], w1 = W_in[NI + i];
        float a = fmaf(Y0, w0, fmaf(Y1, w1, b_in[i]));
        float x = a * a;
        float q = fmaf(x, D5, D4);
        q = fmaf(q, x, D3);
        q = fmaf(q, x, D2);
        q = fmaf(q, x, 1.0f);
        q = fmaf(q, x, 1.0f);
        float s = __builtin_amdgcn_rcpf(q) * W_out[i];
        g0 = fmaf(s, w0, g0);
        g1 = fmaf(s, w1, g1);
      }
      float nX0 = Y0 + e0, nX1 = Y1 + e1;
      Y0 = g0 - X0;
      Y1 = g1 - X1;
      X0 = nX0;
      X1 = nX1;
    }
    out[row] = make_float4(X0, X1, Y0, Y1);
  }
}

extern "C" void kernel_launch(void* const* d_in, const int* in_sizes, int n_in,
                              void* d_out, int out_size, void* d_ws, size_t ws_size,
                              hipStream_t stream) {
  const float4* z = (const float4*)d_in[0];
  const float* W_in = (const float*)d_in[1];
  const float* W_out = (const float*)d_in[2];
  const float* b_in = (const float*)d_in[3];
  const float* eta = (const float*)d_in[4];
  float4* out = (float4*)d_out;

  int batch = in_sizes[0] / 4;  // 2,000,000 rows

  if (ws_size >= 642 * sizeof(float)) {
    float* P = (float*)d_ws;
    henon_prep<<<1, 64, 0, stream>>>(W_in, W_out, b_in, eta, P);
    int ngroups = (batch + 3) >> 2;
    int blocks = (ngroups + 255) / 256;
    henon4<<<blocks, 256, 0, stream>>>(z, P, out, batch);
  } else {
    int blocks = (batch + 255) / 256;
    henon_raw<<<blocks, 256, 0, stream>>>(z, W_in, W_out, b_in, eta, out, batch);
  }
}